// Round 7
// baseline (132.964 us; speedup 1.0000x reference)
//
#include <hip/hip_runtime.h>
#include <hip/hip_bf16.h>

#define Bn 4096
#define Dk 1024
#define EPSF 1e-7f

typedef float f32x16 __attribute__((ext_vector_type(16)));

__device__ __forceinline__ void async_copy16(const void* g, void* l) {
    __builtin_amdgcn_global_load_lds((__attribute__((address_space(1))) void*)(uintptr_t)g,
                                     (__attribute__((address_space(3))) void*)l, 16, 0, 0);
}

// -------- Kernel 1: L2-normalize rows -> fp8 e4m3 (x8 prescale); exact f32 diag; zero sums ----
__global__ __launch_bounds__(256)
void nrm_kernel(const float4* __restrict__ left, const float4* __restrict__ right,
                unsigned* __restrict__ lnb8, unsigned* __restrict__ rnb8,
                float* __restrict__ diag, float* __restrict__ rowsum,
                float* __restrict__ colsum)
{
    const int row = blockIdx.x;
    const int t = threadIdx.x;
    const int idx = row * (Dk / 4) + t;
    const float4 l = left[idx];
    const float4 r = right[idx];
    float sl = l.x * l.x + l.y * l.y + l.z * l.z + l.w * l.w;
    float sr = r.x * r.x + r.y * r.y + r.z * r.z + r.w * r.w;
    float slr = l.x * r.x + l.y * r.y + l.z * r.z + l.w * r.w;
    #pragma unroll
    for (int off = 1; off < 64; off <<= 1) {
        sl += __shfl_xor(sl, off);
        sr += __shfl_xor(sr, off);
        slr += __shfl_xor(slr, off);
    }
    __shared__ float red[3][4];
    const int wave = t >> 6, lane = t & 63;
    if (lane == 0) { red[0][wave] = sl; red[1][wave] = sr; red[2][wave] = slr; }
    __syncthreads();
    sl = red[0][0] + red[0][1] + red[0][2] + red[0][3];
    sr = red[1][0] + red[1][1] + red[1][2] + red[1][3];
    const float invl = 1.0f / sqrtf(fmaxf(sl, EPSF));
    const float invr = 1.0f / sqrtf(fmaxf(sr, EPSF));
    const float sL = 8.0f * invl;
    const float sR = 8.0f * invr;
    int pkL = __builtin_amdgcn_cvt_pk_fp8_f32(l.x * sL, l.y * sL, 0, false);
    pkL = __builtin_amdgcn_cvt_pk_fp8_f32(l.z * sL, l.w * sL, pkL, true);
    int pkR = __builtin_amdgcn_cvt_pk_fp8_f32(r.x * sR, r.y * sR, 0, false);
    pkR = __builtin_amdgcn_cvt_pk_fp8_f32(r.z * sR, r.w * sR, pkR, true);
    lnb8[idx] = (unsigned)pkL;
    rnb8[idx] = (unsigned)pkR;
    if (t == 0) {
        const float d = red[2][0] + red[2][1] + red[2][2] + red[2][3];
        diag[row] = d * invl * invr;
        rowsum[row] = 0.f;
        colsum[row] = 0.f;
    }
}

// -------- Kernel 2: S = ln . rn^T, fp8 mfma_f32_32x32x16, ping-pong LDS, raw-barrier pipeline --
// vs R6: 32x32x16 frags (2x2 per wave) halve the MFMA instruction count at equal FLOP and
// equal LDS traffic; live input regs drop 32->8; __launch_bounds__(256,3) allows 3 blocks/CU.
// Pipeline: "s_waitcnt vmcnt(4); s_barrier" waits only the previous tile's 4 async loads
// (prefetch stays in flight across the barrier); post-compute barrier is execution-only.
__global__ __launch_bounds__(256, 3)
void gemm_sm_kernel(const unsigned char* __restrict__ lnb8,
                    const unsigned char* __restrict__ rnb8,
                    const float* __restrict__ temp,
                    float* __restrict__ rowsum, float* __restrict__ colsum)
{
    __shared__ __align__(16) unsigned char As[2][128 * 64];
    __shared__ __align__(16) unsigned char Bs[2][128 * 64];

    const int tid = threadIdx.x;
    const int wave = tid >> 6;
    const int lane = tid & 63;
    const int bm0 = blockIdx.y * 128;
    const int bn0 = blockIdx.x * 128;

    // ---- staging: wave w stages rows [32w, 32w+32), 2 insts of 16 rows per matrix
    const int srow = lane >> 2;          // row within 16-row inst group
    const int sj = lane & 3;             // chunk16 slot within 64-B row
    int goff[2];                         // global byte offset (row*Dk + swizzled col)
    int lofs[2];                         // LDS base offset (wave-uniform)
    #pragma unroll
    for (int i = 0; i < 2; ++i) {
        const int rloc = wave * 32 + i * 16 + srow;
        goff[i] = rloc * Dk + 16 * (sj ^ ((rloc >> 1) & 3));   // even-key swizzle
        lofs[i] = (wave * 32 + i * 16) * 64;
    }
    const unsigned char* baseA = lnb8 + (size_t)bm0 * Dk;
    const unsigned char* baseB = rnb8 + (size_t)bn0 * Dk;

    // ---- compute-side: 32x32x16 fp8; A/B row = lane&31, k-group = lane>>5 (8 fp8 each)
    const int wm = (wave & 1) * 64;
    const int wn = (wave >> 1) * 64;
    const int c31 = lane & 31;
    const int hl = lane >> 5;
    const int key = c31 & 6;             // even XOR key at chunk8 granularity (= row&6)
    int arow[2], brow[2];
    #pragma unroll
    for (int i = 0; i < 2; ++i) {
        arow[i] = (wm + i * 32 + c31) * 64;
        brow[i] = (wn + i * 32 + c31) * 64;
    }

    f32x16 acc[2][2];
    #pragma unroll
    for (int i = 0; i < 2; ++i)
        #pragma unroll
        for (int j = 0; j < 2; ++j)
            acc[i][j] = (f32x16)(0.f);

    // prologue: stage tile 0 into buffer 0
    #pragma unroll
    for (int i = 0; i < 2; ++i) {
        async_copy16(baseA + goff[i], &As[0][lofs[i]]);
        async_copy16(baseB + goff[i], &Bs[0][lofs[i]]);
    }

    #pragma unroll 2
    for (int it = 0; it < 16; ++it) {
        const int cur = it & 1;
        const int nxt = cur ^ 1;
        const int knext = ((it + 1) & 15) * 64;   // wraps on last iter (dummy reload)
        #pragma unroll
        for (int i = 0; i < 2; ++i) {
            async_copy16(baseA + goff[i] + knext, &As[nxt][lofs[i]]);
            async_copy16(baseB + goff[i] + knext, &Bs[nxt][lofs[i]]);
        }
        // wait only the PREVIOUS tile's 4 loads; prefetch stays in flight
        asm volatile("s_waitcnt vmcnt(4)\n\ts_barrier" ::: "memory");
        #pragma unroll
        for (int ks = 0; ks < 4; ++ks) {
            const int co = 8 * (((ks << 1) + hl) ^ key);   // swizzled chunk8 offset
            long af[2], bf[2];
            #pragma unroll
            for (int i = 0; i < 2; ++i) af[i] = *(const long*)(&As[cur][arow[i] + co]);
            #pragma unroll
            for (int i = 0; i < 2; ++i) bf[i] = *(const long*)(&Bs[cur][brow[i] + co]);
            #pragma unroll
            for (int mi = 0; mi < 2; ++mi)
                #pragma unroll
                for (int ni = 0; ni < 2; ++ni)
                    acc[mi][ni] = __builtin_amdgcn_mfma_f32_32x32x16_fp8_fp8(
                        af[mi], bf[ni], acc[mi][ni], 0, 0, 0);
        }
        // execution-only barrier: everyone done reading `cur` before it is restaged
        asm volatile("s_barrier" ::: "memory");
    }

    // epilogue: undo the 8x8 prescale (2^-6, exact), then p = exp(scale*s - scale)
    const float scale = __expf(temp[0]);
    const float dq = 0.015625f * scale;  // 2^-6 * scale
    #pragma unroll
    for (int mi = 0; mi < 2; ++mi)
        #pragma unroll
        for (int ni = 0; ni < 2; ++ni)
            #pragma unroll
            for (int r = 0; r < 16; ++r)
                acc[mi][ni][r] = __expf(dq * acc[mi][ni][r] - scale);

    // C/D 32x32 layout: col = lane&31, row = (r&3) + 8*(r>>2) + 4*hl
    #pragma unroll
    for (int mi = 0; mi < 2; ++mi) {
        #pragma unroll
        for (int r = 0; r < 16; ++r) {
            float v = acc[mi][0][r] + acc[mi][1][r];
            v += __shfl_xor(v, 1);
            v += __shfl_xor(v, 2);
            v += __shfl_xor(v, 4);
            v += __shfl_xor(v, 8);
            v += __shfl_xor(v, 16);
            if (c31 == 0)
                atomicAdd(&rowsum[bm0 + wm + mi * 32 + (r & 3) + 8 * (r >> 2) + 4 * hl], v);
        }
    }
    #pragma unroll
    for (int ni = 0; ni < 2; ++ni) {
        float v = 0.f;
        #pragma unroll
        for (int mi = 0; mi < 2; ++mi)
            #pragma unroll
            for (int r = 0; r < 16; ++r)
                v += acc[mi][ni][r];
        v += __shfl_xor(v, 32);
        if (hl == 0)
            atomicAdd(&colsum[bn0 + wn + ni * 32 + c31], v);
    }
}

// -------- Kernel 3: final scalar loss --------
__global__ __launch_bounds__(256)
void loss_kernel(const float* __restrict__ diag, const float* __restrict__ rowsum,
                 const float* __restrict__ colsum, const float* __restrict__ temp,
                 float* __restrict__ out)
{
    const int t = threadIdx.x;
    const float scale = __expf(temp[0]);
    float dL = 0.f, dR = 0.f;
    for (int i = t; i < Bn; i += 256) {
        const float e = __expf(scale * (diag[i] - 1.0f));
        dL += e * __builtin_amdgcn_rcpf(rowsum[i]);
        dR += e * __builtin_amdgcn_rcpf(colsum[i]);
    }
    #pragma unroll
    for (int off = 1; off < 64; off <<= 1) {
        dL += __shfl_xor(dL, off);
        dR += __shfl_xor(dR, off);
    }
    __shared__ float rd[2][4];
    const int wave = t >> 6, lane = t & 63;
    if (lane == 0) { rd[0][wave] = dL; rd[1][wave] = dR; }
    __syncthreads();
    if (t == 0) {
        dL = rd[0][0] + rd[0][1] + rd[0][2] + rd[0][3];
        dR = rd[1][0] + rd[1][1] + rd[1][2] + rd[1][3];
        const float logeps = logf(EPSF);
        const float log1m = logf(1.0f - EPSF);
        const float lossL = -(dL * log1m + ((float)Bn - dL) * logeps);
        const float lossR = -(dR * log1m + ((float)Bn - dR) * logeps);
        out[0] = (lossL + lossR) * 0.5f / (float)Bn;
    }
}

extern "C" void kernel_launch(void* const* d_in, const int* in_sizes, int n_in,
                              void* d_out, int out_size, void* d_ws, size_t ws_size,
                              hipStream_t stream) {
    (void)in_sizes; (void)n_in; (void)out_size; (void)ws_size;
    const float* left = (const float*)d_in[0];
    const float* right = (const float*)d_in[1];
    const float* temp = (const float*)d_in[2];

    char* ws = (char*)d_ws;
    unsigned char* lnb8 = (unsigned char*)ws;                       // 4 MiB
    unsigned char* rnb8 = (unsigned char*)(ws + (size_t)Bn * Dk);   // 4 MiB
    float* diag = (float*)(ws + 2 * (size_t)Bn * Dk);
    float* rowsum = diag + Bn;
    float* colsum = rowsum + Bn;

    nrm_kernel<<<Bn, 256, 0, stream>>>((const float4*)left, (const float4*)right,
                                       (unsigned*)lnb8, (unsigned*)rnb8, diag, rowsum, colsum);
    dim3 g2(Bn / 128, Bn / 128);
    gemm_sm_kernel<<<g2, 256, 0, stream>>>(lnb8, rnb8, temp, rowsum, colsum);
    loss_kernel<<<1, 256, 0, stream>>>(diag, rowsum, colsum, temp, (float*)d_out);
}

// Round 8
// 126.521 us; speedup vs baseline: 1.0509x; 1.0509x over previous
//
#include <hip/hip_runtime.h>
#include <hip/hip_bf16.h>

#define Bn 4096
#define Dk 1024
#define EPSF 1e-7f

typedef float f32x4 __attribute__((ext_vector_type(4)));

__device__ __forceinline__ void async_copy16(const void* g, void* l) {
    __builtin_amdgcn_global_load_lds((__attribute__((address_space(1))) void*)(uintptr_t)g,
                                     (__attribute__((address_space(3))) void*)l, 16, 0, 0);
}

// -------- Kernel 1: L2-normalize rows -> fp8 e4m3 (x8 prescale); exact f32 diag; zero sums ----
__global__ __launch_bounds__(256)
void nrm_kernel(const float4* __restrict__ left, const float4* __restrict__ right,
                unsigned* __restrict__ lnb8, unsigned* __restrict__ rnb8,
                float* __restrict__ diag, float* __restrict__ rowsum,
                float* __restrict__ colsum)
{
    const int row = blockIdx.x;
    const int t = threadIdx.x;
    const int idx = row * (Dk / 4) + t;
    const float4 l = left[idx];
    const float4 r = right[idx];
    float sl = l.x * l.x + l.y * l.y + l.z * l.z + l.w * l.w;
    float sr = r.x * r.x + r.y * r.y + r.z * r.z + r.w * r.w;
    float slr = l.x * r.x + l.y * r.y + l.z * r.z + l.w * r.w;
    #pragma unroll
    for (int off = 1; off < 64; off <<= 1) {
        sl += __shfl_xor(sl, off);
        sr += __shfl_xor(sr, off);
        slr += __shfl_xor(slr, off);
    }
    __shared__ float red[3][4];
    const int wave = t >> 6, lane = t & 63;
    if (lane == 0) { red[0][wave] = sl; red[1][wave] = sr; red[2][wave] = slr; }
    __syncthreads();
    sl = red[0][0] + red[0][1] + red[0][2] + red[0][3];
    sr = red[1][0] + red[1][1] + red[1][2] + red[1][3];
    const float invl = 1.0f / sqrtf(fmaxf(sl, EPSF));
    const float invr = 1.0f / sqrtf(fmaxf(sr, EPSF));
    const float sL = 8.0f * invl;
    const float sR = 8.0f * invr;
    int pkL = __builtin_amdgcn_cvt_pk_fp8_f32(l.x * sL, l.y * sL, 0, false);
    pkL = __builtin_amdgcn_cvt_pk_fp8_f32(l.z * sL, l.w * sL, pkL, true);
    int pkR = __builtin_amdgcn_cvt_pk_fp8_f32(r.x * sR, r.y * sR, 0, false);
    pkR = __builtin_amdgcn_cvt_pk_fp8_f32(r.z * sR, r.w * sR, pkR, true);
    lnb8[idx] = (unsigned)pkL;
    rnb8[idx] = (unsigned)pkR;
    if (t == 0) {
        const float d = red[2][0] + red[2][1] + red[2][2] + red[2][3];
        diag[row] = d * invl * invr;
        rowsum[row] = 0.f;
        colsum[row] = 0.f;
    }
}

// -------- Kernel 2: S = ln . rn^T, fp8 16x16x32 MFMA, WAVE-PRIVATE LDS, ZERO BARRIERS ----
// Each wave stages its own 64x64 A and B slices (4 KB each; 4+4 global_load_lds/iter) into
// a private ping-pong region. Pipeline discipline is purely wave-local:
//   issue 8 prefetch loads -> s_waitcnt vmcnt(8) (prev tile done, prefetch in flight)
//   -> compute. No s_barrier at all: waves never couple, so a stalled block can't idle
// the SIMDs (R7 showed MfmaUtil 24% from barrier coupling at ~2 blocks/CU).
// Staging traffic doubles vs shared tiles (536 MB, L2-served ~15 us, overlapped).
// s_waitcnt lgkmcnt(0) before restaging orders own ds_reads vs incoming LDS writes.
__global__ __launch_bounds__(256, 2)
void gemm_sm_kernel(const unsigned char* __restrict__ lnb8,
                    const unsigned char* __restrict__ rnb8,
                    const float* __restrict__ temp,
                    float* __restrict__ rowsum, float* __restrict__ colsum)
{
    __shared__ __align__(16) unsigned char SA[2][4][4096];
    __shared__ __align__(16) unsigned char SB[2][4][4096];

    const int tid = threadIdx.x;
    const int wave = tid >> 6;
    const int lane = tid & 63;
    const int bm0 = blockIdx.y * 128;
    const int bn0 = blockIdx.x * 128;

    const int wm = (wave & 1) * 64;
    const int wn = (wave >> 1) * 64;

    // ---- staging: this wave stages A rows [wm,wm+64) and B rows [wn,wn+64)
    // inst i covers slice rows [16i,16i+16); lane -> row 16i+(lane>>2), chunk16 slot lane&3
    const int srow = lane >> 2;
    const int sj = lane & 3;
    const int gcol = 16 * (sj ^ ((srow >> 1) & 3));   // even-key swizzle (i*16 doesn't affect key)
    const unsigned char* baseA = lnb8 + (size_t)(bm0 + wm) * Dk;
    const unsigned char* baseB = rnb8 + (size_t)(bn0 + wn) * Dk;
    const int goff = srow * Dk + gcol;                // + i*16*Dk + k0 at issue

    // ---- compute-side: 16x16x32 fp8; slice-local offsets (same formula for A and B)
    const int quad = lane >> 4;
    const int r16 = lane & 15;
    const int key = r16 & 6;
    int aoff[4];
    #pragma unroll
    for (int i = 0; i < 4; ++i)
        aoff[i] = (i * 16 + r16) * 64 + 8 * (quad ^ key);
    const int ks1d = 8 * ((4 + quad) ^ key) - 8 * (quad ^ key);

    f32x4 acc[4][4];
    #pragma unroll
    for (int i = 0; i < 4; ++i)
        #pragma unroll
        for (int j = 0; j < 4; ++j)
            acc[i][j] = (f32x4){0.f, 0.f, 0.f, 0.f};

    // prologue: stage tile 0 into buffer 0
    #pragma unroll
    for (int i = 0; i < 4; ++i) {
        async_copy16(baseA + goff + i * 16 * Dk, &SA[0][wave][i * 1024]);
        async_copy16(baseB + goff + i * 16 * Dk, &SB[0][wave][i * 1024]);
    }

    #pragma unroll 2
    for (int it = 0; it < 16; ++it) {
        const int cur = it & 1;
        const int nxt = cur ^ 1;
        const int knext = ((it + 1) & 15) * 64;   // wraps on last iter (dummy reload)
        // own ds_reads of iter it-1 fully done before overwriting buf `nxt`
        asm volatile("s_waitcnt lgkmcnt(0)" ::: "memory");
        #pragma unroll
        for (int i = 0; i < 4; ++i) {
            async_copy16(baseA + goff + i * 16 * Dk + knext, &SA[nxt][wave][i * 1024]);
            async_copy16(baseB + goff + i * 16 * Dk + knext, &SB[nxt][wave][i * 1024]);
        }
        // wait only the PREVIOUS tile's 8 loads; prefetch stays in flight; NO barrier
        asm volatile("s_waitcnt vmcnt(8)" ::: "memory");
        const unsigned char* As = &SA[cur][wave][0];
        const unsigned char* Bs = &SB[cur][wave][0];
        #pragma unroll
        for (int ks = 0; ks < 2; ++ks) {
            const int d = ks ? ks1d : 0;
            long af[4], bf[4];
            #pragma unroll
            for (int i = 0; i < 4; ++i) af[i] = *(const long*)(As + aoff[i] + d);
            #pragma unroll
            for (int i = 0; i < 4; ++i) bf[i] = *(const long*)(Bs + aoff[i] + d);
            #pragma unroll
            for (int mi = 0; mi < 4; ++mi)
                #pragma unroll
                for (int ni = 0; ni < 4; ++ni)
                    acc[mi][ni] = __builtin_amdgcn_mfma_f32_16x16x32_fp8_fp8(
                        af[mi], bf[ni], acc[mi][ni], 0, 0, 0);
        }
    }

    // epilogue: undo the 8x8 prescale (2^-6, exact), then p = exp(scale*s - scale)
    const float scale = __expf(temp[0]);
    const float dq = 0.015625f * scale;  // 2^-6 * scale
    #pragma unroll
    for (int mi = 0; mi < 4; ++mi)
        #pragma unroll
        for (int ni = 0; ni < 4; ++ni)
            #pragma unroll
            for (int r = 0; r < 4; ++r)
                acc[mi][ni][r] = __expf(dq * acc[mi][ni][r] - scale);

    // C/D layout: col = lane&15, row = quad*4 + reg
    #pragma unroll
    for (int mi = 0; mi < 4; ++mi) {
        #pragma unroll
        for (int r = 0; r < 4; ++r) {
            float v = acc[mi][0][r] + acc[mi][1][r] + acc[mi][2][r] + acc[mi][3][r];
            v += __shfl_xor(v, 1);
            v += __shfl_xor(v, 2);
            v += __shfl_xor(v, 4);
            v += __shfl_xor(v, 8);
            if (r16 == 0)
                atomicAdd(&rowsum[bm0 + wm + mi * 16 + quad * 4 + r], v);
        }
    }
    #pragma unroll
    for (int ni = 0; ni < 4; ++ni) {
        float v = 0.f;
        #pragma unroll
        for (int mi = 0; mi < 4; ++mi)
            #pragma unroll
            for (int r = 0; r < 4; ++r)
                v += acc[mi][ni][r];
        v += __shfl_xor(v, 16);
        v += __shfl_xor(v, 32);
        if (quad == 0)
            atomicAdd(&colsum[bn0 + wn + ni * 16 + r16], v);
    }
}

// -------- Kernel 3: final scalar loss --------
__global__ __launch_bounds__(256)
void loss_kernel(const float* __restrict__ diag, const float* __restrict__ rowsum,
                 const float* __restrict__ colsum, const float* __restrict__ temp,
                 float* __restrict__ out)
{
    const int t = threadIdx.x;
    const float scale = __expf(temp[0]);
    float dL = 0.f, dR = 0.f;
    for (int i = t; i < Bn; i += 256) {
        const float e = __expf(scale * (diag[i] - 1.0f));
        dL += e * __builtin_amdgcn_rcpf(rowsum[i]);
        dR += e * __builtin_amdgcn_rcpf(colsum[i]);
    }
    #pragma unroll
    for (int off = 1; off < 64; off <<= 1) {
        dL += __shfl_xor(dL, off);
        dR += __shfl_xor(dR, off);
    }
    __shared__ float rd[2][4];
    const int wave = t >> 6, lane = t & 63;
    if (lane == 0) { rd[0][wave] = dL; rd[1][wave] = dR; }
    __syncthreads();
    if (t == 0) {
        dL = rd[0][0] + rd[0][1] + rd[0][2] + rd[0][3];
        dR = rd[1][0] + rd[1][1] + rd[1][2] + rd[1][3];
        const float logeps = logf(EPSF);
        const float log1m = logf(1.0f - EPSF);
        const float lossL = -(dL * log1m + ((float)Bn - dL) * logeps);
        const float lossR = -(dR * log1m + ((float)Bn - dR) * logeps);
        out[0] = (lossL + lossR) * 0.5f / (float)Bn;
    }
}

extern "C" void kernel_launch(void* const* d_in, const int* in_sizes, int n_in,
                              void* d_out, int out_size, void* d_ws, size_t ws_size,
                              hipStream_t stream) {
    (void)in_sizes; (void)n_in; (void)out_size; (void)ws_size;
    const float* left = (const float*)d_in[0];
    const float* right = (const float*)d_in[1];
    const float* temp = (const float*)d_in[2];

    char* ws = (char*)d_ws;
    unsigned char* lnb8 = (unsigned char*)ws;                       // 4 MiB
    unsigned char* rnb8 = (unsigned char*)(ws + (size_t)Bn * Dk);   // 4 MiB
    float* diag = (float*)(ws + 2 * (size_t)Bn * Dk);
    float* rowsum = diag + Bn;
    float* colsum = rowsum + Bn;

    nrm_kernel<<<Bn, 256, 0, stream>>>((const float4*)left, (const float4*)right,
                                       (unsigned*)lnb8, (unsigned*)rnb8, diag, rowsum, colsum);
    dim3 g2(Bn / 128, Bn / 128);
    gemm_sm_kernel<<<g2, 256, 0, stream>>>(lnb8, rnb8, temp, rowsum, colsum);
    loss_kernel<<<1, 256, 0, stream>>>(diag, rowsum, colsum, temp, (float*)d_out);
}

// Round 9
// 115.787 us; speedup vs baseline: 1.1483x; 1.0927x over previous
//
#include <hip/hip_runtime.h>
#include <hip/hip_bf16.h>

#define Bn 4096
#define Dk 1024
#define EPSF 1e-7f

typedef float f32x4 __attribute__((ext_vector_type(4)));
typedef long long2_t __attribute__((ext_vector_type(2)));

__device__ __forceinline__ void async_copy16(const void* g, void* l) {
    __builtin_amdgcn_global_load_lds((__attribute__((address_space(1))) void*)(uintptr_t)g,
                                     (__attribute__((address_space(3))) void*)l, 16, 0, 0);
}

// -------- Kernel 1: L2-normalize -> fp8 e4m3 (x8 prescale), K-INTERLEAVED layout ----
// Within each 64-B K-group, chunk8s are stored as [0,4 | 1,5 | 2,6 | 3,7]: granule q holds
// k-bytes [8q..8q+7] and [32+8q..32+8q+7]. Both matrices use the same permutation, so all
// dot products are unchanged; the gemm reads each lane's two k-step fragments with ONE
// ds_read_b128. Thread t handles k=4t..4t+3 (one dword), written to the permuted offset.
__global__ __launch_bounds__(256)
void nrm_kernel(const float4* __restrict__ left, const float4* __restrict__ right,
                unsigned char* __restrict__ lnb8, unsigned char* __restrict__ rnb8,
                float* __restrict__ diag, float* __restrict__ rowsum,
                float* __restrict__ colsum)
{
    const int row = blockIdx.x;
    const int t = threadIdx.x;
    const int idx = row * (Dk / 4) + t;
    const float4 l = left[idx];
    const float4 r = right[idx];
    float sl = l.x * l.x + l.y * l.y + l.z * l.z + l.w * l.w;
    float sr = r.x * r.x + r.y * r.y + r.z * r.z + r.w * r.w;
    float slr = l.x * r.x + l.y * r.y + l.z * r.z + l.w * r.w;
    #pragma unroll
    for (int off = 1; off < 64; off <<= 1) {
        sl += __shfl_xor(sl, off);
        sr += __shfl_xor(sr, off);
        slr += __shfl_xor(slr, off);
    }
    __shared__ float red[3][4];
    const int wave = t >> 6, lane = t & 63;
    if (lane == 0) { red[0][wave] = sl; red[1][wave] = sr; red[2][wave] = slr; }
    __syncthreads();
    sl = red[0][0] + red[0][1] + red[0][2] + red[0][3];
    sr = red[1][0] + red[1][1] + red[1][2] + red[1][3];
    const float invl = 1.0f / sqrtf(fmaxf(sl, EPSF));
    const float invr = 1.0f / sqrtf(fmaxf(sr, EPSF));
    const float sL = 8.0f * invl;
    const float sR = 8.0f * invr;
    int pkL = __builtin_amdgcn_cvt_pk_fp8_f32(l.x * sL, l.y * sL, 0, false);
    pkL = __builtin_amdgcn_cvt_pk_fp8_f32(l.z * sL, l.w * sL, pkL, true);
    int pkR = __builtin_amdgcn_cvt_pk_fp8_f32(r.x * sR, r.y * sR, 0, false);
    pkR = __builtin_amdgcn_cvt_pk_fp8_f32(r.z * sR, r.w * sR, pkR, true);
    // permuted destination: group g = k>>6; within group, granule q=(kl&31)>>3,
    // half = kl>>5, byte = (g<<6) + (q<<4) + (half<<3) + (kl&7)
    const int k0 = 4 * t;
    const int g = k0 >> 6;
    const int kl = k0 & 63;
    const int dst = row * Dk + (g << 6) + (((kl & 31) >> 3) << 4) + ((kl >> 5) << 3) + (kl & 7);
    *(unsigned*)(lnb8 + dst) = (unsigned)pkL;
    *(unsigned*)(rnb8 + dst) = (unsigned)pkR;
    if (t == 0) {
        const float d = red[2][0] + red[2][1] + red[2][2] + red[2][3];
        diag[row] = d * invl * invr;
        rowsum[row] = 0.f;
        colsum[row] = 0.f;
    }
}

// -------- Kernel 2: S = ln . rn^T, fp8 16x16x32 MFMA, R6 pipeline + b128 LDS reads ----
// R6's proven skeleton: shared 128x128 tile, BK=64, ping-pong LDS, raw "s_waitcnt vmcnt(4);
// s_barrier" (prefetch stays in flight), execution-only post-barrier. Changes:
//  - K-interleaved operands (from nrm): one ds_read_b128 per row-frag yields both k-step
//    fragments -> 8 ds_read_b128/iter instead of 16 ds_read_b64 (halves LDS inst stream).
//    Bank-exact: lanes 0-7 of a quad-phase cover all 32 banks once; 8-15 repeat (2-way, free).
//  - __launch_bounds__(256,3): ~3 blocks/CU for latency hiding (LDS 32 KB/block).
__global__ __launch_bounds__(256, 3)
void gemm_sm_kernel(const unsigned char* __restrict__ lnb8,
                    const unsigned char* __restrict__ rnb8,
                    const float* __restrict__ temp,
                    float* __restrict__ rowsum, float* __restrict__ colsum)
{
    __shared__ __align__(16) unsigned char As[2][128 * 64];
    __shared__ __align__(16) unsigned char Bs[2][128 * 64];

    const int tid = threadIdx.x;
    const int wave = tid >> 6;
    const int lane = tid & 63;
    const int bm0 = blockIdx.y * 128;
    const int bn0 = blockIdx.x * 128;

    // ---- staging: wave w stages rows [32w, 32w+32), 2 insts of 16 rows per matrix
    const int srow = lane >> 2;          // row within 16-row inst group
    const int sj = lane & 3;             // granule16 slot within 64-B row
    int goff[2];
    int lofs[2];
    #pragma unroll
    for (int i = 0; i < 2; ++i) {
        const int rloc = wave * 32 + i * 16 + srow;
        goff[i] = rloc * Dk + 16 * (sj ^ ((rloc >> 1) & 3));   // granule16 swizzle
        lofs[i] = (wave * 32 + i * 16) * 64;
    }
    const unsigned char* baseA = lnb8 + (size_t)bm0 * Dk;
    const unsigned char* baseB = rnb8 + (size_t)bn0 * Dk;

    // ---- compute-side: lane quad q's two k-fragments live in granule q (16 B) of each row
    const int wm = (wave & 1) * 64;
    const int wn = (wave >> 1) * 64;
    const int quad = lane >> 4;
    const int r16 = lane & 15;
    const int skey = (r16 >> 1) & 3;
    int aoff[4], boff[4];
    #pragma unroll
    for (int i = 0; i < 4; ++i) {
        aoff[i] = (wm + i * 16 + r16) * 64 + 16 * (quad ^ skey);
        boff[i] = (wn + i * 16 + r16) * 64 + 16 * (quad ^ skey);
    }

    f32x4 acc[4][4];
    #pragma unroll
    for (int i = 0; i < 4; ++i)
        #pragma unroll
        for (int j = 0; j < 4; ++j)
            acc[i][j] = (f32x4){0.f, 0.f, 0.f, 0.f};

    // prologue: stage tile 0 into buffer 0
    #pragma unroll
    for (int i = 0; i < 2; ++i) {
        async_copy16(baseA + goff[i], &As[0][lofs[i]]);
        async_copy16(baseB + goff[i], &Bs[0][lofs[i]]);
    }

    #pragma unroll 2
    for (int it = 0; it < 16; ++it) {
        const int cur = it & 1;
        const int nxt = cur ^ 1;
        const int knext = ((it + 1) & 15) * 64;   // wraps on last iter (dummy reload)
        #pragma unroll
        for (int i = 0; i < 2; ++i) {
            async_copy16(baseA + goff[i] + knext, &As[nxt][lofs[i]]);
            async_copy16(baseB + goff[i] + knext, &Bs[nxt][lofs[i]]);
        }
        // wait only the PREVIOUS tile's 4 loads; prefetch stays in flight
        asm volatile("s_waitcnt vmcnt(4)\n\ts_barrier" ::: "memory");
        long2_t af01[4], bf01[4];
        #pragma unroll
        for (int i = 0; i < 4; ++i) af01[i] = *(const long2_t*)(&As[cur][aoff[i]]);
        #pragma unroll
        for (int i = 0; i < 4; ++i) bf01[i] = *(const long2_t*)(&Bs[cur][boff[i]]);
        #pragma unroll
        for (int mi = 0; mi < 4; ++mi)
            #pragma unroll
            for (int ni = 0; ni < 4; ++ni)
                acc[mi][ni] = __builtin_amdgcn_mfma_f32_16x16x32_fp8_fp8(
                    af01[mi].x, bf01[ni].x, acc[mi][ni], 0, 0, 0);
        #pragma unroll
        for (int mi = 0; mi < 4; ++mi)
            #pragma unroll
            for (int ni = 0; ni < 4; ++ni)
                acc[mi][ni] = __builtin_amdgcn_mfma_f32_16x16x32_fp8_fp8(
                    af01[mi].y, bf01[ni].y, acc[mi][ni], 0, 0, 0);
        // execution-only barrier: everyone done reading `cur` before it is restaged
        asm volatile("s_barrier" ::: "memory");
    }

    // epilogue: undo the 8x8 prescale (2^-6, exact), then p = exp(scale*s - scale)
    const float scale = __expf(temp[0]);
    const float dq = 0.015625f * scale;  // 2^-6 * scale
    #pragma unroll
    for (int mi = 0; mi < 4; ++mi)
        #pragma unroll
        for (int ni = 0; ni < 4; ++ni)
            #pragma unroll
            for (int r = 0; r < 4; ++r)
                acc[mi][ni][r] = __expf(dq * acc[mi][ni][r] - scale);

    // C/D layout: col = lane&15, row = quad*4 + reg
    #pragma unroll
    for (int mi = 0; mi < 4; ++mi) {
        #pragma unroll
        for (int r = 0; r < 4; ++r) {
            float v = acc[mi][0][r] + acc[mi][1][r] + acc[mi][2][r] + acc[mi][3][r];
            v += __shfl_xor(v, 1);
            v += __shfl_xor(v, 2);
            v += __shfl_xor(v, 4);
            v += __shfl_xor(v, 8);
            if (r16 == 0)
                atomicAdd(&rowsum[bm0 + wm + mi * 16 + quad * 4 + r], v);
        }
    }
    #pragma unroll
    for (int ni = 0; ni < 4; ++ni) {
        float v = 0.f;
        #pragma unroll
        for (int mi = 0; mi < 4; ++mi)
            #pragma unroll
            for (int r = 0; r < 4; ++r)
                v += acc[mi][ni][r];
        v += __shfl_xor(v, 16);
        v += __shfl_xor(v, 32);
        if (quad == 0)
            atomicAdd(&colsum[bn0 + wn + ni * 16 + r16], v);
    }
}

// -------- Kernel 3: final scalar loss --------
__global__ __launch_bounds__(256)
void loss_kernel(const float* __restrict__ diag, const float* __restrict__ rowsum,
                 const float* __restrict__ colsum, const float* __restrict__ temp,
                 float* __restrict__ out)
{
    const int t = threadIdx.x;
    const float scale = __expf(temp[0]);
    float dL = 0.f, dR = 0.f;
    for (int i = t; i < Bn; i += 256) {
        const float e = __expf(scale * (diag[i] - 1.0f));
        dL += e * __builtin_amdgcn_rcpf(rowsum[i]);
        dR += e * __builtin_amdgcn_rcpf(colsum[i]);
    }
    #pragma unroll
    for (int off = 1; off < 64; off <<= 1) {
        dL += __shfl_xor(dL, off);
        dR += __shfl_xor(dR, off);
    }
    __shared__ float rd[2][4];
    const int wave = t >> 6, lane = t & 63;
    if (lane == 0) { rd[0][wave] = dL; rd[1][wave] = dR; }
    __syncthreads();
    if (t == 0) {
        dL = rd[0][0] + rd[0][1] + rd[0][2] + rd[0][3];
        dR = rd[1][0] + rd[1][1] + rd[1][2] + rd[1][3];
        const float logeps = logf(EPSF);
        const float log1m = logf(1.0f - EPSF);
        const float lossL = -(dL * log1m + ((float)Bn - dL) * logeps);
        const float lossR = -(dR * log1m + ((float)Bn - dR) * logeps);
        out[0] = (lossL + lossR) * 0.5f / (float)Bn;
    }
}

extern "C" void kernel_launch(void* const* d_in, const int* in_sizes, int n_in,
                              void* d_out, int out_size, void* d_ws, size_t ws_size,
                              hipStream_t stream) {
    (void)in_sizes; (void)n_in; (void)out_size; (void)ws_size;
    const float* left = (const float*)d_in[0];
    const float* right = (const float*)d_in[1];
    const float* temp = (const float*)d_in[2];

    char* ws = (char*)d_ws;
    unsigned char* lnb8 = (unsigned char*)ws;                       // 4 MiB
    unsigned char* rnb8 = (unsigned char*)(ws + (size_t)Bn * Dk);   // 4 MiB
    float* diag = (float*)(ws + 2 * (size_t)Bn * Dk);
    float* rowsum = diag + Bn;
    float* colsum = rowsum + Bn;

    nrm_kernel<<<Bn, 256, 0, stream>>>((const float4*)left, (const float4*)right,
                                       lnb8, rnb8, diag, rowsum, colsum);
    dim3 g2(Bn / 128, Bn / 128);
    gemm_sm_kernel<<<g2, 256, 0, stream>>>(lnb8, rnb8, temp, rowsum, colsum);
    loss_kernel<<<1, 256, 0, stream>>>(diag, rowsum, colsum, temp, (float*)d_out);
}

// Round 10
// 114.209 us; speedup vs baseline: 1.1642x; 1.0138x over previous
//
#include <hip/hip_runtime.h>
#include <hip/hip_bf16.h>

#define Bn 4096
#define Dk 1024
#define EPSF 1e-7f

typedef float f32x4 __attribute__((ext_vector_type(4)));
typedef long long2_t __attribute__((ext_vector_type(2)));

__device__ __forceinline__ void async_copy16(const void* g, void* l) {
    __builtin_amdgcn_global_load_lds((__attribute__((address_space(1))) void*)(uintptr_t)g,
                                     (__attribute__((address_space(3))) void*)l, 16, 0, 0);
}

// -------- Kernel 1: L2-normalize -> fp8 e4m3 (x8 prescale), K-INTERLEAVED layout ----
// Granule q (16 B) of each 64-B K-group holds k-bytes [8q..8q+7] and [32+8q..32+8q+7];
// both operands share the permutation so dot products are unchanged, and one ds_read_b128
// yields a lane's two k-step fragments.
__global__ __launch_bounds__(256)
void nrm_kernel(const float4* __restrict__ left, const float4* __restrict__ right,
                unsigned char* __restrict__ lnb8, unsigned char* __restrict__ rnb8,
                float* __restrict__ diag, float* __restrict__ rowsum,
                float* __restrict__ colsum)
{
    const int row = blockIdx.x;
    const int t = threadIdx.x;
    const int idx = row * (Dk / 4) + t;
    const float4 l = left[idx];
    const float4 r = right[idx];
    float sl = l.x * l.x + l.y * l.y + l.z * l.z + l.w * l.w;
    float sr = r.x * r.x + r.y * r.y + r.z * r.z + r.w * r.w;
    float slr = l.x * r.x + l.y * r.y + l.z * r.z + l.w * r.w;
    #pragma unroll
    for (int off = 1; off < 64; off <<= 1) {
        sl += __shfl_xor(sl, off);
        sr += __shfl_xor(sr, off);
        slr += __shfl_xor(slr, off);
    }
    __shared__ float red[3][4];
    const int wave = t >> 6, lane = t & 63;
    if (lane == 0) { red[0][wave] = sl; red[1][wave] = sr; red[2][wave] = slr; }
    __syncthreads();
    sl = red[0][0] + red[0][1] + red[0][2] + red[0][3];
    sr = red[1][0] + red[1][1] + red[1][2] + red[1][3];
    const float invl = 1.0f / sqrtf(fmaxf(sl, EPSF));
    const float invr = 1.0f / sqrtf(fmaxf(sr, EPSF));
    const float sL = 8.0f * invl;
    const float sR = 8.0f * invr;
    int pkL = __builtin_amdgcn_cvt_pk_fp8_f32(l.x * sL, l.y * sL, 0, false);
    pkL = __builtin_amdgcn_cvt_pk_fp8_f32(l.z * sL, l.w * sL, pkL, true);
    int pkR = __builtin_amdgcn_cvt_pk_fp8_f32(r.x * sR, r.y * sR, 0, false);
    pkR = __builtin_amdgcn_cvt_pk_fp8_f32(r.z * sR, r.w * sR, pkR, true);
    const int k0 = 4 * t;
    const int g = k0 >> 6;
    const int kl = k0 & 63;
    const int dst = row * Dk + (g << 6) + (((kl & 31) >> 3) << 4) + ((kl >> 5) << 3) + (kl & 7);
    *(unsigned*)(lnb8 + dst) = (unsigned)pkL;
    *(unsigned*)(rnb8 + dst) = (unsigned)pkR;
    if (t == 0) {
        const float d = red[2][0] + red[2][1] + red[2][2] + red[2][3];
        diag[row] = d * invl * invr;
        rowsum[row] = 0.f;
        colsum[row] = 0.f;
    }
}

// -------- Kernel 2: S = ln . rn^T, fp8 16x16x32 MFMA, 128x256 tile (LDS-BW-optimized) ----
// Diagnosis R4-R9: MfmaUtil pinned ~25% because every variant moved ~375 LDS bytes per
// MFMA (16 KB stage + 32 KB read per 128-MFMA block-iter) against ~85-128 B/cyc/CU.
// This version: block 128x256, wave tile 64x128 (4 waves 2x2 over MxN) -> 72 KB per
// 256 MFMA = 281 B/MFMA (-25%). acc[4][8]=128 AGPRs (non-scaled MFMA keeps AGPR path).
// Pipeline unchanged from R6/R9: ping-pong LDS, raw "s_waitcnt vmcnt(6); s_barrier"
// (prefetch in flight across barrier), execution-only post-barrier, K-interleaved b128 reads.
__global__ __launch_bounds__(256, 2)
void gemm_sm_kernel(const unsigned char* __restrict__ lnb8,
                    const unsigned char* __restrict__ rnb8,
                    const float* __restrict__ temp,
                    float* __restrict__ rowsum, float* __restrict__ colsum)
{
    __shared__ __align__(16) unsigned char As[2][128 * 64];
    __shared__ __align__(16) unsigned char Bs[2][256 * 64];

    const int tid = threadIdx.x;
    const int wave = tid >> 6;
    const int lane = tid & 63;
    const int bm0 = blockIdx.y * 128;
    const int bn0 = blockIdx.x * 256;

    // ---- staging: wave stages A rows [32w,32w+32) (2 insts) and B rows [64w,64w+64) (4 insts)
    const int srow = lane >> 2;          // row within 16-row inst group
    const int sj = lane & 3;             // granule16 slot within 64-B row
    int goffA[2], lofsA[2];
    #pragma unroll
    for (int i = 0; i < 2; ++i) {
        const int rloc = wave * 32 + i * 16 + srow;
        goffA[i] = rloc * Dk + 16 * (sj ^ ((rloc >> 1) & 3));
        lofsA[i] = (wave * 32 + i * 16) * 64;
    }
    int goffB[4], lofsB[4];
    #pragma unroll
    for (int i = 0; i < 4; ++i) {
        const int rloc = wave * 64 + i * 16 + srow;
        goffB[i] = rloc * Dk + 16 * (sj ^ ((rloc >> 1) & 3));
        lofsB[i] = (wave * 64 + i * 16) * 64;
    }
    const unsigned char* baseA = lnb8 + (size_t)bm0 * Dk;
    const unsigned char* baseB = rnb8 + (size_t)bn0 * Dk;

    // ---- compute-side: wave tile 64x128; wm=(wave&1)*64 (M), wn=(wave>>1)*128 (N)
    const int wm = (wave & 1) * 64;
    const int wn = (wave >> 1) * 128;
    const int quad = lane >> 4;
    const int r16 = lane & 15;
    const int skey = (r16 >> 1) & 3;
    const int gq = 16 * (quad ^ skey);
    int aoff[4], boff[8];
    #pragma unroll
    for (int i = 0; i < 4; ++i)
        aoff[i] = (wm + i * 16 + r16) * 64 + gq;
    #pragma unroll
    for (int i = 0; i < 8; ++i)
        boff[i] = (wn + i * 16 + r16) * 64 + gq;

    f32x4 acc[4][8];
    #pragma unroll
    for (int i = 0; i < 4; ++i)
        #pragma unroll
        for (int j = 0; j < 8; ++j)
            acc[i][j] = (f32x4){0.f, 0.f, 0.f, 0.f};

    // prologue: stage tile 0 into buffer 0
    #pragma unroll
    for (int i = 0; i < 2; ++i) async_copy16(baseA + goffA[i], &As[0][lofsA[i]]);
    #pragma unroll
    for (int i = 0; i < 4; ++i) async_copy16(baseB + goffB[i], &Bs[0][lofsB[i]]);

    #pragma unroll 2
    for (int it = 0; it < 16; ++it) {
        const int cur = it & 1;
        const int nxt = cur ^ 1;
        const int knext = ((it + 1) & 15) * 64;   // wraps on last iter (dummy reload)
        #pragma unroll
        for (int i = 0; i < 2; ++i) async_copy16(baseA + goffA[i] + knext, &As[nxt][lofsA[i]]);
        #pragma unroll
        for (int i = 0; i < 4; ++i) async_copy16(baseB + goffB[i] + knext, &Bs[nxt][lofsB[i]]);
        // wait only the PREVIOUS tile's 6 loads; prefetch stays in flight
        asm volatile("s_waitcnt vmcnt(6)\n\ts_barrier" ::: "memory");
        long2_t af01[4], bf01[8];
        #pragma unroll
        for (int i = 0; i < 4; ++i) af01[i] = *(const long2_t*)(&As[cur][aoff[i]]);
        #pragma unroll
        for (int i = 0; i < 8; ++i) bf01[i] = *(const long2_t*)(&Bs[cur][boff[i]]);
        #pragma unroll
        for (int mi = 0; mi < 4; ++mi)
            #pragma unroll
            for (int ni = 0; ni < 8; ++ni)
                acc[mi][ni] = __builtin_amdgcn_mfma_f32_16x16x32_fp8_fp8(
                    af01[mi].x, bf01[ni].x, acc[mi][ni], 0, 0, 0);
        #pragma unroll
        for (int mi = 0; mi < 4; ++mi)
            #pragma unroll
            for (int ni = 0; ni < 8; ++ni)
                acc[mi][ni] = __builtin_amdgcn_mfma_f32_16x16x32_fp8_fp8(
                    af01[mi].y, bf01[ni].y, acc[mi][ni], 0, 0, 0);
        // execution-only barrier: everyone done reading `cur` before it is restaged
        asm volatile("s_barrier" ::: "memory");
    }

    // epilogue: undo the 8x8 prescale (2^-6, exact), then p = exp(scale*s - scale)
    const float scale = __expf(temp[0]);
    const float dq = 0.015625f * scale;  // 2^-6 * scale
    #pragma unroll
    for (int mi = 0; mi < 4; ++mi)
        #pragma unroll
        for (int ni = 0; ni < 8; ++ni)
            #pragma unroll
            for (int r = 0; r < 4; ++r)
                acc[mi][ni][r] = __expf(dq * acc[mi][ni][r] - scale);

    // C/D layout: col = lane&15, row = quad*4 + reg
    #pragma unroll
    for (int mi = 0; mi < 4; ++mi) {
        #pragma unroll
        for (int r = 0; r < 4; ++r) {
            float v = 0.f;
            #pragma unroll
            for (int ni = 0; ni < 8; ++ni) v += acc[mi][ni][r];
            v += __shfl_xor(v, 1);
            v += __shfl_xor(v, 2);
            v += __shfl_xor(v, 4);
            v += __shfl_xor(v, 8);
            if (r16 == 0)
                atomicAdd(&rowsum[bm0 + wm + mi * 16 + quad * 4 + r], v);
        }
    }
    #pragma unroll
    for (int ni = 0; ni < 8; ++ni) {
        float v = 0.f;
        #pragma unroll
        for (int mi = 0; mi < 4; ++mi)
            #pragma unroll
            for (int r = 0; r < 4; ++r)
                v += acc[mi][ni][r];
        v += __shfl_xor(v, 16);
        v += __shfl_xor(v, 32);
        if (quad == 0)
            atomicAdd(&colsum[bn0 + wn + ni * 16 + r16], v);
    }
}

// -------- Kernel 3: final scalar loss --------
__global__ __launch_bounds__(256)
void loss_kernel(const float* __restrict__ diag, const float* __restrict__ rowsum,
                 const float* __restrict__ colsum, const float* __restrict__ temp,
                 float* __restrict__ out)
{
    const int t = threadIdx.x;
    const float scale = __expf(temp[0]);
    float dL = 0.f, dR = 0.f;
    for (int i = t; i < Bn; i += 256) {
        const float e = __expf(scale * (diag[i] - 1.0f));
        dL += e * __builtin_amdgcn_rcpf(rowsum[i]);
        dR += e * __builtin_amdgcn_rcpf(colsum[i]);
    }
    #pragma unroll
    for (int off = 1; off < 64; off <<= 1) {
        dL += __shfl_xor(dL, off);
        dR += __shfl_xor(dR, off);
    }
    __shared__ float rd[2][4];
    const int wave = t >> 6, lane = t & 63;
    if (lane == 0) { rd[0][wave] = dL; rd[1][wave] = dR; }
    __syncthreads();
    if (t == 0) {
        dL = rd[0][0] + rd[0][1] + rd[0][2] + rd[0][3];
        dR = rd[1][0] + rd[1][1] + rd[1][2] + rd[1][3];
        const float logeps = logf(EPSF);
        const float log1m = logf(1.0f - EPSF);
        const float lossL = -(dL * log1m + ((float)Bn - dL) * logeps);
        const float lossR = -(dR * log1m + ((float)Bn - dR) * logeps);
        out[0] = (lossL + lossR) * 0.5f / (float)Bn;
    }
}

extern "C" void kernel_launch(void* const* d_in, const int* in_sizes, int n_in,
                              void* d_out, int out_size, void* d_ws, size_t ws_size,
                              hipStream_t stream) {
    (void)in_sizes; (void)n_in; (void)out_size; (void)ws_size;
    const float* left = (const float*)d_in[0];
    const float* right = (const float*)d_in[1];
    const float* temp = (const float*)d_in[2];

    char* ws = (char*)d_ws;
    unsigned char* lnb8 = (unsigned char*)ws;                       // 4 MiB
    unsigned char* rnb8 = (unsigned char*)(ws + (size_t)Bn * Dk);   // 4 MiB
    float* diag = (float*)(ws + 2 * (size_t)Bn * Dk);
    float* rowsum = diag + Bn;
    float* colsum = rowsum + Bn;

    nrm_kernel<<<Bn, 256, 0, stream>>>((const float4*)left, (const float4*)right,
                                       lnb8, rnb8, diag, rowsum, colsum);
    dim3 g2(Bn / 256, Bn / 128);
    gemm_sm_kernel<<<g2, 256, 0, stream>>>(lnb8, rnb8, temp, rowsum, colsum);
    loss_kernel<<<1, 256, 0, stream>>>(diag, rowsum, colsum, temp, (float*)d_out);
}